// Round 1
// baseline (207.940 us; speedup 1.0000x reference)
//
#include <hip/hip_runtime.h>

#define BATCH   16384
#define INDIM   1024
#define OUTDIM  256

constexpr int ROWS = 32;          // rows per block
constexpr int KP   = 472;         // padded concatenated K (LDS row stride, mult of 4)
// segment layout in coef row (all offsets 16B-aligned; pads zero-filled):
//   cA4 @   0 (len 70, pad to 72)   -> basis0 rows 0..71 (1024 rows, safe)
//   cD4 @  72 (len 70, pad to 144)  -> basis1 rows 0..71 (512, safe)
//   cD3 @ 144 (len 134, pad to 280) -> basis2 rows 0..135 (256, safe)
//   cD2 @ 280 (len 128)             -> basis3 rows 0..127 (exact)
//   cD1 @ 408 (len 64)              -> basis4 rows 0..63  (exact)

// symmetric extension: X(t) for t in [-6, N+5]
__device__ __forceinline__ float symx(const float* __restrict__ in, int N, int t) {
    if (t < 0)  t = -1 - t;
    if (t >= N) t = 2 * N - 1 - t;
    return in[t];
}

// one dwt level: cA[i] = sum_k X(2i-6+k)*LOR[k], cD likewise with HIR.
// M = floor((N+7)/2) outputs for cA; first nD outputs for cD.
__device__ __forceinline__ void dwt_level(const float* __restrict__ in, int N, int M,
                                          float* __restrict__ outA,
                                          float* __restrict__ outD, int nD,
                                          int ht) {
    // db4 dec_lo reversed (correlation form), matches jax reference exactly
    constexpr float LOR[8] = { 0.2303778133088965f,   0.7148465705529157f,
                               0.6308807679298589f,  -0.027983769416859854f,
                              -0.18703481171909309f,  0.030841381835560764f,
                               0.0328830116668852f,  -0.010597401785069032f };
    constexpr float HIR[8] = {-0.010597401785069032f, -0.0328830116668852f,
                               0.030841381835560764f,  0.18703481171909309f,
                              -0.027983769416859854f, -0.6308807679298589f,
                               0.7148465705529157f,   -0.2303778133088965f };
    for (int i = ht; i < M; i += 128) {
        const int base = 2 * i - 6;
        float a = 0.f, d = 0.f;
        if (base >= 0 && base + 7 < N) {      // interior: branch-free loads
            #pragma unroll
            for (int k = 0; k < 8; ++k) {
                const float v = in[base + k];
                a = fmaf(v, LOR[k], a);
                d = fmaf(v, HIR[k], d);
            }
        } else {                              // symmetric boundary
            #pragma unroll
            for (int k = 0; k < 8; ++k) {
                const float v = symx(in, N, base + k);
                a = fmaf(v, LOR[k], a);
                d = fmaf(v, HIR[k], d);
            }
        }
        outA[i] = a;
        if (i < nD) outD[i] = d;
    }
}

extern "C" __global__ __launch_bounds__(256, 2)
void wkan_fused(const float* __restrict__ x,
                const float* __restrict__ b0, const float* __restrict__ b1,
                const float* __restrict__ b2, const float* __restrict__ b3,
                const float* __restrict__ b4,
                float* __restrict__ out)
{
    extern __shared__ float smem[];
    float* coef = smem;                 // [ROWS][KP] = 60416 B
    float* wbuf = smem + ROWS * KP;     // 2 slots x (1024 + 520) floats = 12352 B

    const int tid  = threadIdx.x;
    const int row0 = blockIdx.x * ROWS;

    // zero coef so pad columns contribute 0 to the GEMM
    for (int i = tid; i < ROWS * KP / 4; i += 256)
        ((float4*)coef)[i] = float4{0.f, 0.f, 0.f, 0.f};
    __syncthreads();

    // ---------------- DWT phase: 2 rows in parallel (128 threads each) -------
    const int slot = tid >> 7;          // 0/1
    const int ht   = tid & 127;
    float* bufA = wbuf + slot * 1544;   // holds x (1024), then cA2 (261)
    float* bufB = bufA + 1024;          // holds cA1 (515), then cA3 (134)

    for (int it = 0; it < ROWS / 2; ++it) {
        const int r = it * 2 + slot;
        float* crow = coef + r * KP;
        const float* xrow = x + (size_t)(row0 + r) * INDIM;
        ((float4*)bufA)[ht]       = ((const float4*)xrow)[ht];
        ((float4*)bufA)[ht + 128] = ((const float4*)xrow)[ht + 128];
        __syncthreads();
        dwt_level(bufA, 1024, 515, bufB, crow + 408, 64, ht);   // L1: cD1 (64 kept)
        __syncthreads();
        dwt_level(bufB, 515, 261, bufA, crow + 280, 128, ht);   // L2: cD2 (128 kept)
        __syncthreads();
        dwt_level(bufA, 261, 134, bufB, crow + 144, 134, ht);   // L3: cD3 (134)
        __syncthreads();
        dwt_level(bufB, 134, 70, crow, crow + 72, 70, ht);      // L4: cA4 + cD4
        __syncthreads();
    }

    // ---------------- GEMM phase: [32 x 472] * [472 x 256] -------------------
    // thread tile: 4 rows x 8 cols; wave reads coef with 2-way broadcast (free)
    const int rg = tid >> 5;            // 0..7 -> rows rg*4 .. rg*4+3
    const int cg = tid & 31;            // cols cg*8 .. cg*8+7

    float acc[4][8];
    #pragma unroll
    for (int r = 0; r < 4; ++r)
        #pragma unroll
        for (int c = 0; c < 8; ++c) acc[r][c] = 0.f;

    const float* Bs[5]  = { b0, b1, b2, b3, b4 };
    const int    off[5] = { 0, 72, 144, 280, 408 };
    const int    l4[5]  = { 72, 72, 136, 128, 64 };

    for (int s = 0; s < 5; ++s) {
        const float* __restrict__ B = Bs[s];
        const int o = off[s], L = l4[s];
        for (int k = 0; k < L; k += 4) {
            float4 bb[4][2];
            #pragma unroll
            for (int kk = 0; kk < 4; ++kk) {
                const float* bp = B + (size_t)(k + kk) * OUTDIM + cg * 8;
                bb[kk][0] = *(const float4*)(bp);
                bb[kk][1] = *(const float4*)(bp + 4);
            }
            #pragma unroll
            for (int rr = 0; rr < 4; ++rr) {
                const float4 c4 = *(const float4*)(coef + (rg * 4 + rr) * KP + o + k);
                const float cv[4] = { c4.x, c4.y, c4.z, c4.w };
                #pragma unroll
                for (int kk = 0; kk < 4; ++kk) {
                    acc[rr][0] = fmaf(cv[kk], bb[kk][0].x, acc[rr][0]);
                    acc[rr][1] = fmaf(cv[kk], bb[kk][0].y, acc[rr][1]);
                    acc[rr][2] = fmaf(cv[kk], bb[kk][0].z, acc[rr][2]);
                    acc[rr][3] = fmaf(cv[kk], bb[kk][0].w, acc[rr][3]);
                    acc[rr][4] = fmaf(cv[kk], bb[kk][1].x, acc[rr][4]);
                    acc[rr][5] = fmaf(cv[kk], bb[kk][1].y, acc[rr][5]);
                    acc[rr][6] = fmaf(cv[kk], bb[kk][1].z, acc[rr][6]);
                    acc[rr][7] = fmaf(cv[kk], bb[kk][1].w, acc[rr][7]);
                }
            }
        }
    }

    #pragma unroll
    for (int rr = 0; rr < 4; ++rr) {
        float* op = out + (size_t)(row0 + rg * 4 + rr) * OUTDIM + cg * 8;
        *(float4*)(op)     = float4{ acc[rr][0], acc[rr][1], acc[rr][2], acc[rr][3] };
        *(float4*)(op + 4) = float4{ acc[rr][4], acc[rr][5], acc[rr][6], acc[rr][7] };
    }
}

extern "C" void kernel_launch(void* const* d_in, const int* in_sizes, int n_in,
                              void* d_out, int out_size, void* d_ws, size_t ws_size,
                              hipStream_t stream) {
    const float* x  = (const float*)d_in[0];
    const float* b0 = (const float*)d_in[1];
    const float* b1 = (const float*)d_in[2];
    const float* b2 = (const float*)d_in[3];
    const float* b3 = (const float*)d_in[4];
    const float* b4 = (const float*)d_in[5];
    float* out = (float*)d_out;

    const size_t shmem = (size_t)(ROWS * KP + 2 * 1544) * sizeof(float); // 72768 B
    hipLaunchKernelGGL(wkan_fused, dim3(BATCH / ROWS), dim3(256), shmem, stream,
                       x, b0, b1, b2, b3, b4, out);
}

// Round 2
// 176.049 us; speedup vs baseline: 1.1812x; 1.1812x over previous
//
#include <hip/hip_runtime.h>

#define BATCH   16384
#define INDIM   1024
#define OUTDIM  256

// padded concatenated-K layout (all segment offsets 16B-aligned, pads = 0):
//   cA4 @   0 len 70  (pad 70..72)
//   cD4 @  72 len 70  (pad 142..144)
//   cD3 @ 144 len 134 (pad 278..280)
//   cD2 @ 280 len 128
//   cD1 @ 408 len 64  (pad 472..480)
constexpr int KP = 480;

// db4 dec filters in correlation form (verified against jax ref in R1)
__device__ __constant__ float LORc[8] = { 0.2303778133088965f,   0.7148465705529157f,
                                          0.6308807679298589f,  -0.027983769416859854f,
                                         -0.18703481171909309f,  0.030841381835560764f,
                                          0.0328830116668852f,  -0.010597401785069032f };
__device__ __constant__ float HIRc[8] = {-0.010597401785069032f, -0.0328830116668852f,
                                          0.030841381835560764f,  0.18703481171909309f,
                                         -0.027983769416859854f, -0.6308807679298589f,
                                          0.7148465705529157f,   -0.2303778133088965f };

__device__ __forceinline__ float symx(const float* __restrict__ in, int N, int t) {
    if (t < 0)  t = -1 - t;
    if (t >= N) t = 2 * N - 1 - t;
    return in[t];
}

// one dwt level, executed by ONE wave (lane-strided). outA/outD may be LDS or global.
__device__ __forceinline__ void dwt_level(const float* __restrict__ in, int N, int M,
                                          float* __restrict__ outA,
                                          float* __restrict__ outD, int nD, int lane) {
    for (int i = lane; i < M; i += 64) {
        const int base = 2 * i - 6;
        float a = 0.f, d = 0.f;
        if (base >= 0 && base + 7 < N) {
            #pragma unroll
            for (int k = 0; k < 8; ++k) {
                const float v = in[base + k];
                a = fmaf(v, LORc[k], a);
                d = fmaf(v, HIRc[k], d);
            }
        } else {
            #pragma unroll
            for (int k = 0; k < 8; ++k) {
                const float v = symx(in, N, base + k);
                a = fmaf(v, LORc[k], a);
                d = fmaf(v, HIRc[k], d);
            }
        }
        outA[i] = a;
        if (i < nD) outD[i] = d;
    }
}

// ---------------- kernel 1: per-row DWT, one wave per row --------------------
extern "C" __global__ __launch_bounds__(256)
void dwt_ws(const float* __restrict__ x, float* __restrict__ coef)
{
    __shared__ float buf[4][1544];          // per-wave: x/cA2 (1024) + cA1/cA3 (520)
    const int wid  = threadIdx.x >> 6;
    const int lane = threadIdx.x & 63;
    const int row  = blockIdx.x * 4 + wid;

    float* bufA = buf[wid];
    float* bufB = bufA + 1024;
    const float* xrow = x + (size_t)row * INDIM;
    float* crow = coef + (size_t)row * KP;

    #pragma unroll
    for (int j = 0; j < 4; ++j)
        ((float4*)bufA)[lane + 64 * j] = ((const float4*)xrow)[lane + 64 * j];
    __syncthreads();
    dwt_level(bufA, 1024, 515, bufB, crow + 408, 64, lane);   // L1: cA1 + cD1[:64]
    __syncthreads();
    dwt_level(bufB, 515, 261, bufA, crow + 280, 128, lane);   // L2: cA2 + cD2[:128]
    __syncthreads();
    dwt_level(bufA, 261, 134, bufB, crow + 144, 134, lane);   // L3: cA3 + cD3
    __syncthreads();
    dwt_level(bufB, 134, 70, crow, crow + 72, 70, lane);      // L4: cA4 + cD4
    // zero the pad slots so the padded-K GEMM is exact
    if (lane < 14) {
        const int padidx[14] = {70,71,142,143,278,279,472,473,474,475,476,477,478,479};
        crow[padidx[lane]] = 0.f;
    }
}

// ---------------- kernel 2: pack bases into Bp[480][256] ---------------------
extern "C" __global__ __launch_bounds__(256)
void pack_b(const float* __restrict__ b0, const float* __restrict__ b1,
            const float* __restrict__ b2, const float* __restrict__ b3,
            const float* __restrict__ b4, float* __restrict__ Bp)
{
    const int k = blockIdx.x;
    const int n = threadIdx.x;
    float v = 0.f;
    if      (k < 70)              v = b0[(size_t)k * OUTDIM + n];
    else if (k >= 72  && k < 142) v = b1[(size_t)(k - 72)  * OUTDIM + n];
    else if (k >= 144 && k < 278) v = b2[(size_t)(k - 144) * OUTDIM + n];
    else if (k >= 280 && k < 408) v = b3[(size_t)(k - 280) * OUTDIM + n];
    else if (k >= 408 && k < 472) v = b4[(size_t)(k - 408) * OUTDIM + n];
    Bp[(size_t)k * OUTDIM + n] = v;
}

// ---------------- kernel 3: C[16384,256] = A[16384,480] @ Bp[480,256] --------
// BM=64 BN=128 BK=16, 256 threads, 4x8 register tile, double-buffered LDS,
// one barrier per K-tile.
extern "C" __global__ __launch_bounds__(256)
void gemm_f32(const float* __restrict__ A, const float* __restrict__ Bp,
              float* __restrict__ C)
{
    __shared__ float Al[2][16][68];     // stride 68: 16B-aligned rows, 2-way banks
    __shared__ float Bl[2][16][128];

    const int tid = threadIdx.x;
    const int m0 = blockIdx.x * 64;
    const int n0 = blockIdx.y * 128;

    const int sa_m = tid >> 2;          // 0..63
    const int sa_k = (tid & 3) << 2;    // 0,4,8,12
    const int sb_k = tid >> 4;          // 0..15
    const int sb_n = (tid & 15) << 3;   // 0..120

    const float* Ap = A  + (size_t)(m0 + sa_m) * KP + sa_k;
    const float* Bq = Bp + (size_t)sb_k * OUTDIM + n0 + sb_n;

    const int rg = tid >> 4;            // 0..15 -> rows rg*4..rg*4+3
    const int cg = tid & 15;            // 0..15 -> cols cg*8..cg*8+7

    float acc[4][8];
    #pragma unroll
    for (int r = 0; r < 4; ++r)
        #pragma unroll
        for (int c = 0; c < 8; ++c) acc[r][c] = 0.f;

    float4 as, bs0, bs1;
    as  = *(const float4*)Ap;
    bs0 = *(const float4*)Bq;
    bs1 = *(const float4*)(Bq + 4);
    Al[0][sa_k + 0][sa_m] = as.x; Al[0][sa_k + 1][sa_m] = as.y;
    Al[0][sa_k + 2][sa_m] = as.z; Al[0][sa_k + 3][sa_m] = as.w;
    *(float4*)&Bl[0][sb_k][sb_n]     = bs0;
    *(float4*)&Bl[0][sb_k][sb_n + 4] = bs1;
    __syncthreads();

    int cur = 0;
    for (int t = 0; t < KP / 16; ++t) {
        if (t < KP / 16 - 1) {
            as  = *(const float4*)(Ap + (t + 1) * 16);
            bs0 = *(const float4*)(Bq + (size_t)(t + 1) * 16 * OUTDIM);
            bs1 = *(const float4*)(Bq + (size_t)(t + 1) * 16 * OUTDIM + 4);
        }
        #pragma unroll
        for (int k = 0; k < 16; ++k) {
            const float4 av  = *(const float4*)&Al[cur][k][rg << 2];
            const float4 bv0 = *(const float4*)&Bl[cur][k][cg << 3];
            const float4 bv1 = *(const float4*)&Bl[cur][k][(cg << 3) + 4];
            const float aa[4] = {av.x, av.y, av.z, av.w};
            const float bb[8] = {bv0.x, bv0.y, bv0.z, bv0.w, bv1.x, bv1.y, bv1.z, bv1.w};
            #pragma unroll
            for (int r = 0; r < 4; ++r)
                #pragma unroll
                for (int c = 0; c < 8; ++c)
                    acc[r][c] = fmaf(aa[r], bb[c], acc[r][c]);
        }
        if (t < KP / 16 - 1) {
            const int nx = cur ^ 1;
            Al[nx][sa_k + 0][sa_m] = as.x; Al[nx][sa_k + 1][sa_m] = as.y;
            Al[nx][sa_k + 2][sa_m] = as.z; Al[nx][sa_k + 3][sa_m] = as.w;
            *(float4*)&Bl[nx][sb_k][sb_n]     = bs0;
            *(float4*)&Bl[nx][sb_k][sb_n + 4] = bs1;
        }
        __syncthreads();
        cur ^= 1;
    }

    #pragma unroll
    for (int r = 0; r < 4; ++r) {
        float* cp = C + (size_t)(m0 + (rg << 2) + r) * OUTDIM + n0 + (cg << 3);
        *(float4*)cp       = float4{acc[r][0], acc[r][1], acc[r][2], acc[r][3]};
        *(float4*)(cp + 4) = float4{acc[r][4], acc[r][5], acc[r][6], acc[r][7]};
    }
}

// ================= fallback: R1 fused kernel (if ws too small) ===============
constexpr int F_ROWS = 32;
constexpr int F_KP   = 472;

__device__ __forceinline__ void dwt_level_f(const float* __restrict__ in, int N, int M,
                                            float* __restrict__ outA,
                                            float* __restrict__ outD, int nD, int ht) {
    for (int i = ht; i < M; i += 128) {
        const int base = 2 * i - 6;
        float a = 0.f, d = 0.f;
        #pragma unroll
        for (int k = 0; k < 8; ++k) {
            const float v = symx(in, N, base + k);
            a = fmaf(v, LORc[k], a);
            d = fmaf(v, HIRc[k], d);
        }
        outA[i] = a;
        if (i < nD) outD[i] = d;
    }
}

extern "C" __global__ __launch_bounds__(256, 2)
void wkan_fused(const float* __restrict__ x,
                const float* __restrict__ b0, const float* __restrict__ b1,
                const float* __restrict__ b2, const float* __restrict__ b3,
                const float* __restrict__ b4,
                float* __restrict__ out)
{
    extern __shared__ float smem[];
    float* coef = smem;
    float* wbuf = smem + F_ROWS * F_KP;

    const int tid  = threadIdx.x;
    const int row0 = blockIdx.x * F_ROWS;

    for (int i = tid; i < F_ROWS * F_KP / 4; i += 256)
        ((float4*)coef)[i] = float4{0.f, 0.f, 0.f, 0.f};
    __syncthreads();

    const int slot = tid >> 7;
    const int ht   = tid & 127;
    float* bufA = wbuf + slot * 1544;
    float* bufB = bufA + 1024;

    for (int it = 0; it < F_ROWS / 2; ++it) {
        const int r = it * 2 + slot;
        float* crow = coef + r * F_KP;
        const float* xrow = x + (size_t)(row0 + r) * INDIM;
        ((float4*)bufA)[ht]       = ((const float4*)xrow)[ht];
        ((float4*)bufA)[ht + 128] = ((const float4*)xrow)[ht + 128];
        __syncthreads();
        dwt_level_f(bufA, 1024, 515, bufB, crow + 408, 64, ht);
        __syncthreads();
        dwt_level_f(bufB, 515, 261, bufA, crow + 280, 128, ht);
        __syncthreads();
        dwt_level_f(bufA, 261, 134, bufB, crow + 144, 134, ht);
        __syncthreads();
        dwt_level_f(bufB, 134, 70, crow, crow + 72, 70, ht);
        __syncthreads();
    }

    const int rg = tid >> 5;
    const int cg = tid & 31;
    float acc[4][8];
    #pragma unroll
    for (int r = 0; r < 4; ++r)
        #pragma unroll
        for (int c = 0; c < 8; ++c) acc[r][c] = 0.f;

    const float* Bs[5]  = { b0, b1, b2, b3, b4 };
    const int    off[5] = { 0, 72, 144, 280, 408 };
    const int    l4[5]  = { 72, 72, 136, 128, 64 };

    for (int s = 0; s < 5; ++s) {
        const float* __restrict__ B = Bs[s];
        const int o = off[s], L = l4[s];
        for (int k = 0; k < L; k += 4) {
            float4 bb[4][2];
            #pragma unroll
            for (int kk = 0; kk < 4; ++kk) {
                const float* bp = B + (size_t)(k + kk) * OUTDIM + cg * 8;
                bb[kk][0] = *(const float4*)(bp);
                bb[kk][1] = *(const float4*)(bp + 4);
            }
            #pragma unroll
            for (int rr = 0; rr < 4; ++rr) {
                const float4 c4 = *(const float4*)(coef + (rg * 4 + rr) * F_KP + o + k);
                const float cv[4] = { c4.x, c4.y, c4.z, c4.w };
                #pragma unroll
                for (int kk = 0; kk < 4; ++kk) {
                    acc[rr][0] = fmaf(cv[kk], bb[kk][0].x, acc[rr][0]);
                    acc[rr][1] = fmaf(cv[kk], bb[kk][0].y, acc[rr][1]);
                    acc[rr][2] = fmaf(cv[kk], bb[kk][0].z, acc[rr][2]);
                    acc[rr][3] = fmaf(cv[kk], bb[kk][0].w, acc[rr][3]);
                    acc[rr][4] = fmaf(cv[kk], bb[kk][1].x, acc[rr][4]);
                    acc[rr][5] = fmaf(cv[kk], bb[kk][1].y, acc[rr][5]);
                    acc[rr][6] = fmaf(cv[kk], bb[kk][1].z, acc[rr][6]);
                    acc[rr][7] = fmaf(cv[kk], bb[kk][1].w, acc[rr][7]);
                }
            }
        }
    }

    #pragma unroll
    for (int rr = 0; rr < 4; ++rr) {
        float* op = out + (size_t)(row0 + rg * 4 + rr) * OUTDIM + cg * 8;
        *(float4*)(op)     = float4{ acc[rr][0], acc[rr][1], acc[rr][2], acc[rr][3] };
        *(float4*)(op + 4) = float4{ acc[rr][4], acc[rr][5], acc[rr][6], acc[rr][7] };
    }
}

// =============================================================================
extern "C" void kernel_launch(void* const* d_in, const int* in_sizes, int n_in,
                              void* d_out, int out_size, void* d_ws, size_t ws_size,
                              hipStream_t stream) {
    const float* x  = (const float*)d_in[0];
    const float* b0 = (const float*)d_in[1];
    const float* b1 = (const float*)d_in[2];
    const float* b2 = (const float*)d_in[3];
    const float* b3 = (const float*)d_in[4];
    const float* b4 = (const float*)d_in[5];
    float* out = (float*)d_out;

    const size_t needA = (size_t)BATCH * KP * sizeof(float);      // 30.9 MB
    const size_t needB = (size_t)KP * OUTDIM * sizeof(float);     // 0.47 MB

    if (ws_size >= needA + needB) {
        float* wsA = (float*)d_ws;
        float* wsB = wsA + (size_t)BATCH * KP;
        hipLaunchKernelGGL(pack_b, dim3(KP), dim3(256), 0, stream,
                           b0, b1, b2, b3, b4, wsB);
        hipLaunchKernelGGL(dwt_ws, dim3(BATCH / 4), dim3(256), 0, stream, x, wsA);
        hipLaunchKernelGGL(gemm_f32, dim3(BATCH / 64, OUTDIM / 128), dim3(256), 0, stream,
                           wsA, wsB, out);
    } else {
        const size_t shmem = (size_t)(F_ROWS * F_KP + 2 * 1544) * sizeof(float);
        hipLaunchKernelGGL(wkan_fused, dim3(BATCH / F_ROWS), dim3(256), shmem, stream,
                           x, b0, b1, b2, b3, b4, out);
    }
}

// Round 3
// 175.920 us; speedup vs baseline: 1.1820x; 1.0007x over previous
//
#include <hip/hip_runtime.h>
#include <stdint.h>

#define BATCH   16384
#define INDIM   1024
#define OUTDIM  256

// concatenated-K layout (pads = 0):
//  cA4@0 len70(->72) | cD4@72 len70(->144) | cD3@144 len134(->280) | cD2@280 len128 | cD1@408 len64 (->480)
constexpr int KP = 480;

typedef __attribute__((ext_vector_type(8))) short short8;
typedef __attribute__((ext_vector_type(4))) float f32x4;

// db4 dec filters, correlation form (verified vs jax ref in R1/R2)
__device__ __constant__ float LORc[8] = { 0.2303778133088965f,   0.7148465705529157f,
                                          0.6308807679298589f,  -0.027983769416859854f,
                                         -0.18703481171909309f,  0.030841381835560764f,
                                          0.0328830116668852f,  -0.010597401785069032f };
__device__ __constant__ float HIRc[8] = {-0.010597401785069032f, -0.0328830116668852f,
                                          0.030841381835560764f,  0.18703481171909309f,
                                         -0.027983769416859854f, -0.6308807679298589f,
                                          0.7148465705529157f,   -0.2303778133088965f };

__device__ __forceinline__ float symx(const float* __restrict__ in, int N, int t) {
    if (t < 0)  t = -1 - t;
    if (t >= N) t = 2 * N - 1 - t;
    return in[t];
}

__device__ __forceinline__ void dwt_level(const float* __restrict__ in, int N, int M,
                                          float* __restrict__ outA,
                                          float* __restrict__ outD, int nD, int lane) {
    for (int i = lane; i < M; i += 64) {
        const int base = 2 * i - 6;
        float a = 0.f, d = 0.f;
        if (base >= 0 && base + 7 < N) {
            #pragma unroll
            for (int k = 0; k < 8; ++k) {
                const float v = in[base + k];
                a = fmaf(v, LORc[k], a);
                d = fmaf(v, HIRc[k], d);
            }
        } else {
            #pragma unroll
            for (int k = 0; k < 8; ++k) {
                const float v = symx(in, N, base + k);
                a = fmaf(v, LORc[k], a);
                d = fmaf(v, HIRc[k], d);
            }
        }
        outA[i] = a;
        if (i < nD) outD[i] = d;
    }
}

__device__ __forceinline__ ushort f2bf_rne(float f) {
    union { float f; uint32_t u; } v; v.f = f;
    uint32_t r = v.u + 0x7fffu + ((v.u >> 16) & 1u);
    return (ushort)(r >> 16);
}
__device__ __forceinline__ float bf2f(ushort h) {
    union { uint32_t u; float f; } v; v.u = ((uint32_t)h) << 16;
    return v.f;
}

// ---- k1: DWT of identity rows -> Wc[1024][KP]  (Wc[i][j] = coeff_j(e_i)) ----
extern "C" __global__ __launch_bounds__(256)
void dwt_id(float* __restrict__ Wc)
{
    __shared__ float buf[4][1544];
    const int wid  = threadIdx.x >> 6;
    const int lane = threadIdx.x & 63;
    const int row  = blockIdx.x * 4 + wid;      // identity index 0..1023

    float* bufA = buf[wid];
    float* bufB = bufA + 1024;
    float* crow = Wc + (size_t)row * KP;

    for (int j = lane; j < 1024; j += 64) bufA[j] = (j == row) ? 1.f : 0.f;
    __syncthreads();
    dwt_level(bufA, 1024, 515, bufB, crow + 408, 64, lane);
    __syncthreads();
    dwt_level(bufB, 515, 261, bufA, crow + 280, 128, lane);
    __syncthreads();
    dwt_level(bufA, 261, 134, bufB, crow + 144, 134, lane);
    __syncthreads();
    dwt_level(bufB, 134, 70, crow, crow + 72, 70, lane);
    if (lane < 14) {
        const int padidx[14] = {70,71,142,143,278,279,472,473,474,475,476,477,478,479};
        crow[padidx[lane]] = 0.f;
    }
}

// ---- k2: pack bases into Bp[KP][256] (pad rows zero) ------------------------
extern "C" __global__ __launch_bounds__(256)
void pack_b(const float* __restrict__ b0, const float* __restrict__ b1,
            const float* __restrict__ b2, const float* __restrict__ b3,
            const float* __restrict__ b4, float* __restrict__ Bp)
{
    const int k = blockIdx.x;
    const int n = threadIdx.x;
    float v = 0.f;
    if      (k < 70)              v = b0[(size_t)k * OUTDIM + n];
    else if (k >= 72  && k < 142) v = b1[(size_t)(k - 72)  * OUTDIM + n];
    else if (k >= 144 && k < 278) v = b2[(size_t)(k - 144) * OUTDIM + n];
    else if (k >= 280 && k < 408) v = b3[(size_t)(k - 280) * OUTDIM + n];
    else if (k >= 408 && k < 472) v = b4[(size_t)(k - 408) * OUTDIM + n];
    Bp[(size_t)k * OUTDIM + n] = v;
}

// ---- k3: W[1024][256] = Wc[1024][KP] @ Bp[KP][256] (fp32) -------------------
extern "C" __global__ __launch_bounds__(256)
void wgemm(const float* __restrict__ Wc, const float* __restrict__ Bp,
           float* __restrict__ W)
{
    __shared__ float wc[4][KP];
    const int tid = threadIdx.x;
    const int r0  = blockIdx.x * 4;

    #pragma unroll
    for (int r = 0; r < 4; ++r)
        for (int k = tid; k < KP; k += 256)
            wc[r][k] = Wc[(size_t)(r0 + r) * KP + k];
    __syncthreads();

    float acc[4] = {0.f, 0.f, 0.f, 0.f};
    for (int k = 0; k < KP; ++k) {
        const float b = Bp[(size_t)k * OUTDIM + tid];
        #pragma unroll
        for (int r = 0; r < 4; ++r) acc[r] = fmaf(wc[r][k], b, acc[r]);
    }
    #pragma unroll
    for (int r = 0; r < 4; ++r) W[(size_t)(r0 + r) * OUTDIM + tid] = acc[r];
}

// ---- k4: pack W into MFMA-fragment-ordered bf16 hi/lo -----------------------
// Bpk layout (ushort): [chunk 32][nf 16][h 2][lane 64][j 8]
//   element: k = chunk*32 + (lane>>4)*8 + j, n = nf*16 + (lane&15)
extern "C" __global__ __launch_bounds__(256)
void bpack(const float* __restrict__ W, ushort* __restrict__ Bpk)
{
    const int slot  = blockIdx.x * 256 + threadIdx.x;   // 0..32767
    const int chunk = slot >> 10;
    const int nf    = (slot >> 6) & 15;
    const int lane  = slot & 63;
    const int k     = chunk * 32 + (lane >> 4) * 8;
    const int n     = nf * 16 + (lane & 15);

    ushort hi[8], lo[8];
    #pragma unroll
    for (int j = 0; j < 8; ++j) {
        const float w = W[(size_t)(k + j) * OUTDIM + n];
        hi[j] = f2bf_rne(w);
        lo[j] = f2bf_rne(w - bf2f(hi[j]));
    }
    const size_t base = ((size_t)(chunk * 16 + nf) * 2) * 64 * 8 + (size_t)lane * 8;
    #pragma unroll
    for (int j = 0; j < 8; ++j) {
        Bpk[base + j]           = hi[j];
        Bpk[base + 512 + j]     = lo[j];   // h=1 block is 64*8 ushorts later
    }
}

// ---- k5: out[16384,256] = x @ W via 3-term bf16-split MFMA ------------------
// BM=64, BN=256, K=1024 in 32 chunks of 32. 512 thr = 8 waves (2m x 4n),
// wave tile 32m x 64n -> 2 mf x 4 nf fragments of 16x16.
extern "C" __global__ __launch_bounds__(512)
void wkan_mfma(const float* __restrict__ x, const ushort* __restrict__ Bpk,
               float* __restrict__ out)
{
    __shared__ ushort Ah[2][2][2][64][8];   // [h][wm][mf][lane][j]  8 KB
    __shared__ ushort Bb[16][2][64][8];     // [nf][h][lane][j]     32 KB

    const int tid  = threadIdx.x;
    const int lane = tid & 63;
    const int wid  = tid >> 6;
    const int wm   = wid >> 2;
    const int wn   = wid & 3;
    const int row0 = blockIdx.x * 64;

    f32x4 acc[2][4];
    #pragma unroll
    for (int m = 0; m < 2; ++m)
        #pragma unroll
        for (int f = 0; f < 4; ++f) acc[m][f] = f32x4{0.f, 0.f, 0.f, 0.f};

    // staging roles
    const int s_wm   = tid >> 7;            // valid for tid<256
    const int s_mf   = (tid >> 6) & 1;
    const int s_lane = tid & 63;
    const int s_row  = s_wm * 32 + s_mf * 16 + (s_lane & 15);
    const int s_kg   = s_lane >> 4;
    const float* xrow = x + (size_t)(row0 + s_row) * INDIM + s_kg * 8;

    float4 af0, af1;
    uint4  bs0, bs1, bs2, bs3;

    // issue loads for chunk 0
    {
        const ushort* bp = Bpk + (size_t)tid * 8;
        bs0 = *(const uint4*)(bp);
        bs1 = *(const uint4*)(bp + 4096);
        bs2 = *(const uint4*)(bp + 8192);
        bs3 = *(const uint4*)(bp + 12288);
        if (tid < 256) {
            af0 = *(const float4*)(xrow);
            af1 = *(const float4*)(xrow + 4);
        }
    }

    for (int c = 0; c < 32; ++c) {
        // ---- write staged chunk c into LDS ----
        {
            ushort* bbf = &Bb[0][0][0][0] + (size_t)tid * 8;
            *(uint4*)(bbf)         = bs0;
            *(uint4*)(bbf + 4096)  = bs1;
            *(uint4*)(bbf + 8192)  = bs2;
            *(uint4*)(bbf + 12288) = bs3;
        }
        if (tid < 256) {
            const float a[8] = {af0.x, af0.y, af0.z, af0.w, af1.x, af1.y, af1.z, af1.w};
            uint32_t hw[4], lw[4];
            #pragma unroll
            for (int p = 0; p < 4; ++p) {
                const ushort h0 = f2bf_rne(a[2*p]),   h1 = f2bf_rne(a[2*p+1]);
                const ushort l0 = f2bf_rne(a[2*p]   - bf2f(h0));
                const ushort l1 = f2bf_rne(a[2*p+1] - bf2f(h1));
                hw[p] = (uint32_t)h0 | ((uint32_t)h1 << 16);
                lw[p] = (uint32_t)l0 | ((uint32_t)l1 << 16);
            }
            *(uint4*)&Ah[0][s_wm][s_mf][s_lane][0] = uint4{hw[0], hw[1], hw[2], hw[3]};
            *(uint4*)&Ah[1][s_wm][s_mf][s_lane][0] = uint4{lw[0], lw[1], lw[2], lw[3]};
        }
        __syncthreads();

        // ---- issue loads for chunk c+1 (fly during MFMA) ----
        if (c < 31) {
            const ushort* bp = Bpk + (size_t)(c + 1) * 16384 + (size_t)tid * 8;
            bs0 = *(const uint4*)(bp);
            bs1 = *(const uint4*)(bp + 4096);
            bs2 = *(const uint4*)(bp + 8192);
            bs3 = *(const uint4*)(bp + 12288);
            if (tid < 256) {
                af0 = *(const float4*)(xrow + (c + 1) * 32);
                af1 = *(const float4*)(xrow + (c + 1) * 32 + 4);
            }
        }

        // ---- compute chunk c ----
        short8 afr[2][2];   // [h][mf]
        #pragma unroll
        for (int h = 0; h < 2; ++h)
            #pragma unroll
            for (int m = 0; m < 2; ++m)
                afr[h][m] = *(const short8*)&Ah[h][wm][m][lane][0];
        short8 bfr[4][2];   // [nf-local][h]
        #pragma unroll
        for (int f = 0; f < 4; ++f)
            #pragma unroll
            for (int h = 0; h < 2; ++h)
                bfr[f][h] = *(const short8*)&Bb[wn * 4 + f][h][lane][0];

        #pragma unroll
        for (int m = 0; m < 2; ++m)
            #pragma unroll
            for (int f = 0; f < 4; ++f) {
                acc[m][f] = __builtin_amdgcn_mfma_f32_16x16x32_bf16(afr[0][m], bfr[f][0], acc[m][f], 0, 0, 0);
                acc[m][f] = __builtin_amdgcn_mfma_f32_16x16x32_bf16(afr[0][m], bfr[f][1], acc[m][f], 0, 0, 0);
                acc[m][f] = __builtin_amdgcn_mfma_f32_16x16x32_bf16(afr[1][m], bfr[f][0], acc[m][f], 0, 0, 0);
            }
        __syncthreads();
    }

    // ---- C write: D[col=lane&15, row=(lane>>4)*4+r] (verified layout) ----
    #pragma unroll
    for (int m = 0; m < 2; ++m)
        #pragma unroll
        for (int f = 0; f < 4; ++f) {
            const int col = wn * 64 + f * 16 + (lane & 15);
            const int rowb = row0 + wm * 32 + m * 16 + (lane >> 4) * 4;
            #pragma unroll
            for (int r = 0; r < 4; ++r)
                out[(size_t)(rowb + r) * OUTDIM + col] = acc[m][f][r];
        }
}

// ================= fallback: R1 fused kernel (if ws too small) ===============
constexpr int F_ROWS = 32;
constexpr int F_KP   = 472;

__device__ __forceinline__ void dwt_level_f(const float* __restrict__ in, int N, int M,
                                            float* __restrict__ outA,
                                            float* __restrict__ outD, int nD, int ht) {
    for (int i = ht; i < M; i += 128) {
        const int base = 2 * i - 6;
        float a = 0.f, d = 0.f;
        #pragma unroll
        for (int k = 0; k < 8; ++k) {
            const float v = symx(in, N, base + k);
            a = fmaf(v, LORc[k], a);
            d = fmaf(v, HIRc[k], d);
        }
        outA[i] = a;
        if (i < nD) outD[i] = d;
    }
}

extern "C" __global__ __launch_bounds__(256, 2)
void wkan_fused(const float* __restrict__ x,
                const float* __restrict__ b0, const float* __restrict__ b1,
                const float* __restrict__ b2, const float* __restrict__ b3,
                const float* __restrict__ b4,
                float* __restrict__ out)
{
    extern __shared__ float smem[];
    float* coef = smem;
    float* wbuf = smem + F_ROWS * F_KP;

    const int tid  = threadIdx.x;
    const int row0 = blockIdx.x * F_ROWS;

    for (int i = tid; i < F_ROWS * F_KP / 4; i += 256)
        ((float4*)coef)[i] = float4{0.f, 0.f, 0.f, 0.f};
    __syncthreads();

    const int slot = tid >> 7;
    const int ht   = tid & 127;
    float* bufA = wbuf + slot * 1544;
    float* bufB = bufA + 1024;

    for (int it = 0; it < F_ROWS / 2; ++it) {
        const int r = it * 2 + slot;
        float* crow = coef + r * F_KP;
        const float* xrow = x + (size_t)(row0 + r) * INDIM;
        ((float4*)bufA)[ht]       = ((const float4*)xrow)[ht];
        ((float4*)bufA)[ht + 128] = ((const float4*)xrow)[ht + 128];
        __syncthreads();
        dwt_level_f(bufA, 1024, 515, bufB, crow + 408, 64, ht);
        __syncthreads();
        dwt_level_f(bufB, 515, 261, bufA, crow + 280, 128, ht);
        __syncthreads();
        dwt_level_f(bufA, 261, 134, bufB, crow + 144, 134, ht);
        __syncthreads();
        dwt_level_f(bufB, 134, 70, crow, crow + 72, 70, ht);
        __syncthreads();
    }

    const int rg = tid >> 5;
    const int cg = tid & 31;
    float acc[4][8];
    #pragma unroll
    for (int r = 0; r < 4; ++r)
        #pragma unroll
        for (int c = 0; c < 8; ++c) acc[r][c] = 0.f;

    const float* Bs[5]  = { b0, b1, b2, b3, b4 };
    const int    off[5] = { 0, 72, 144, 280, 408 };
    const int    l4[5]  = { 72, 72, 136, 128, 64 };

    for (int s = 0; s < 5; ++s) {
        const float* __restrict__ B = Bs[s];
        const int o = off[s], L = l4[s];
        for (int k = 0; k < L; k += 4) {
            float4 bb[4][2];
            #pragma unroll
            for (int kk = 0; kk < 4; ++kk) {
                const float* bp = B + (size_t)(k + kk) * OUTDIM + cg * 8;
                bb[kk][0] = *(const float4*)(bp);
                bb[kk][1] = *(const float4*)(bp + 4);
            }
            #pragma unroll
            for (int rr = 0; rr < 4; ++rr) {
                const float4 c4 = *(const float4*)(coef + (rg * 4 + rr) * F_KP + o + k);
                const float cv[4] = { c4.x, c4.y, c4.z, c4.w };
                #pragma unroll
                for (int kk = 0; kk < 4; ++kk) {
                    acc[rr][0] = fmaf(cv[kk], bb[kk][0].x, acc[rr][0]);
                    acc[rr][1] = fmaf(cv[kk], bb[kk][0].y, acc[rr][1]);
                    acc[rr][2] = fmaf(cv[kk], bb[kk][0].z, acc[rr][2]);
                    acc[rr][3] = fmaf(cv[kk], bb[kk][0].w, acc[rr][3]);
                    acc[rr][4] = fmaf(cv[kk], bb[kk][1].x, acc[rr][4]);
                    acc[rr][5] = fmaf(cv[kk], bb[kk][1].y, acc[rr][5]);
                    acc[rr][6] = fmaf(cv[kk], bb[kk][1].z, acc[rr][6]);
                    acc[rr][7] = fmaf(cv[kk], bb[kk][1].w, acc[rr][7]);
                }
            }
        }
    }

    #pragma unroll
    for (int rr = 0; rr < 4; ++rr) {
        float* op = out + (size_t)(row0 + rg * 4 + rr) * OUTDIM + cg * 8;
        *(float4*)(op)     = float4{ acc[rr][0], acc[rr][1], acc[rr][2], acc[rr][3] };
        *(float4*)(op + 4) = float4{ acc[rr][4], acc[rr][5], acc[rr][6], acc[rr][7] };
    }
}

// =============================================================================
extern "C" void kernel_launch(void* const* d_in, const int* in_sizes, int n_in,
                              void* d_out, int out_size, void* d_ws, size_t ws_size,
                              hipStream_t stream) {
    const float* x  = (const float*)d_in[0];
    const float* b0 = (const float*)d_in[1];
    const float* b1 = (const float*)d_in[2];
    const float* b2 = (const float*)d_in[3];
    const float* b3 = (const float*)d_in[4];
    const float* b4 = (const float*)d_in[5];
    float* out = (float*)d_out;

    const size_t nWc  = (size_t)1024 * KP;            // fp32
    const size_t nBp  = (size_t)KP * OUTDIM;          // fp32
    const size_t nW   = (size_t)1024 * OUTDIM;        // fp32
    const size_t nBpk = (size_t)1024 * OUTDIM * 2;    // ushort (hi+lo)
    const size_t need = (nWc + nBp + nW) * 4 + nBpk * 2;

    if (ws_size >= need) {
        float*  Wc  = (float*)d_ws;
        float*  Bp  = Wc + nWc;
        float*  W   = Bp + nBp;
        ushort* Bpk = (ushort*)(W + nW);

        hipLaunchKernelGGL(pack_b,  dim3(KP),   dim3(256), 0, stream, b0, b1, b2, b3, b4, Bp);
        hipLaunchKernelGGL(dwt_id,  dim3(256),  dim3(256), 0, stream, Wc);
        hipLaunchKernelGGL(wgemm,   dim3(256),  dim3(256), 0, stream, Wc, Bp, W);
        hipLaunchKernelGGL(bpack,   dim3(128),  dim3(256), 0, stream, W, Bpk);
        hipLaunchKernelGGL(wkan_mfma, dim3(BATCH / 64), dim3(512), 0, stream, x, Bpk, out);
    } else {
        const size_t shmem = (size_t)(F_ROWS * F_KP + 2 * 1544) * sizeof(float);
        hipLaunchKernelGGL(wkan_fused, dim3(BATCH / F_ROWS), dim3(256), shmem, stream,
                           x, b0, b1, b2, b3, b4, out);
    }
}

// Round 4
// 160.898 us; speedup vs baseline: 1.2924x; 1.0934x over previous
//
#include <hip/hip_runtime.h>
#include <stdint.h>

#define BATCH   16384
#define INDIM   1024
#define OUTDIM  256

// concatenated-K layout (pads = 0):
//  cA4@0 len70(->72) | cD4@72 len70(->144) | cD3@144 len134(->280) | cD2@280 len128 | cD1@408 len64 (->480)
constexpr int KP = 480;

typedef __attribute__((ext_vector_type(8))) short short8;
typedef __attribute__((ext_vector_type(4))) float f32x4;

// db4 dec filters, correlation form (verified vs jax ref R1-R3)
__device__ __constant__ float LORc[8] = { 0.2303778133088965f,   0.7148465705529157f,
                                          0.6308807679298589f,  -0.027983769416859854f,
                                         -0.18703481171909309f,  0.030841381835560764f,
                                          0.0328830116668852f,  -0.010597401785069032f };
__device__ __constant__ float HIRc[8] = {-0.010597401785069032f, -0.0328830116668852f,
                                          0.030841381835560764f,  0.18703481171909309f,
                                         -0.027983769416859854f, -0.6308807679298589f,
                                          0.7148465705529157f,   -0.2303778133088965f };

__device__ __forceinline__ float symx(const float* __restrict__ in, int N, int t) {
    if (t < 0)  t = -1 - t;
    if (t >= N) t = 2 * N - 1 - t;
    return in[t];
}

__device__ __forceinline__ void dwt_level(const float* __restrict__ in, int N, int M,
                                          float* __restrict__ outA,
                                          float* __restrict__ outD, int nD, int lane) {
    for (int i = lane; i < M; i += 64) {
        const int base = 2 * i - 6;
        float a = 0.f, d = 0.f;
        if (base >= 0 && base + 7 < N) {
            #pragma unroll
            for (int k = 0; k < 8; ++k) {
                const float v = in[base + k];
                a = fmaf(v, LORc[k], a);
                d = fmaf(v, HIRc[k], d);
            }
        } else {
            #pragma unroll
            for (int k = 0; k < 8; ++k) {
                const float v = symx(in, N, base + k);
                a = fmaf(v, LORc[k], a);
                d = fmaf(v, HIRc[k], d);
            }
        }
        outA[i] = a;
        if (i < nD) outD[i] = d;
    }
}

__device__ __forceinline__ ushort f2bf_rne(float f) {
    union { float f; uint32_t u; } v; v.f = f;
    uint32_t r = v.u + 0x7fffu + ((v.u >> 16) & 1u);
    return (ushort)(r >> 16);
}
__device__ __forceinline__ float bf2f(ushort h) {
    union { uint32_t u; float f; } v; v.u = ((uint32_t)h) << 16;
    return v.f;
}

// split two floats -> packed hi-bf16 word + packed lo-bf16 word (both RNE)
__device__ __forceinline__ void split2(float a0, float a1, uint32_t& hw, uint32_t& lw) {
    const uint32_t u0 = __float_as_uint(a0), u1 = __float_as_uint(a1);
    const uint32_t r0 = u0 + 0x7fffu + ((u0 >> 16) & 1u);
    const uint32_t r1 = u1 + 0x7fffu + ((u1 >> 16) & 1u);
    hw = (r0 >> 16) | (r1 & 0xffff0000u);
    const float l0 = a0 - __uint_as_float(r0 & 0xffff0000u);
    const float l1 = a1 - __uint_as_float(r1 & 0xffff0000u);
    const uint32_t v0 = __float_as_uint(l0), v1 = __float_as_uint(l1);
    const uint32_t s0 = v0 + 0x7fffu + ((v0 >> 16) & 1u);
    const uint32_t s1 = v1 + 0x7fffu + ((v1 >> 16) & 1u);
    lw = (s0 >> 16) | (s1 & 0xffff0000u);
}

// ---- prep1: blocks 0..255 -> identity DWT rows (Wc); blocks 256..375 -> pack Bp
extern "C" __global__ __launch_bounds__(256)
void prep1(const float* __restrict__ b0, const float* __restrict__ b1,
           const float* __restrict__ b2, const float* __restrict__ b3,
           const float* __restrict__ b4,
           float* __restrict__ Wc, float* __restrict__ Bp)
{
    __shared__ float buf[4][1544];
    const int tid = threadIdx.x;
    if (blockIdx.x < 256) {
        const int wid  = tid >> 6;
        const int lane = tid & 63;
        const int row  = blockIdx.x * 4 + wid;     // identity index 0..1023
        float* bufA = buf[wid];
        float* bufB = bufA + 1024;
        float* crow = Wc + (size_t)row * KP;
        for (int j = lane; j < 1024; j += 64) bufA[j] = (j == row) ? 1.f : 0.f;
        __syncthreads();
        dwt_level(bufA, 1024, 515, bufB, crow + 408, 64, lane);
        __syncthreads();
        dwt_level(bufB, 515, 261, bufA, crow + 280, 128, lane);
        __syncthreads();
        dwt_level(bufA, 261, 134, bufB, crow + 144, 134, lane);
        __syncthreads();
        dwt_level(bufB, 134, 70, crow, crow + 72, 70, lane);
        if (lane < 14) {
            const int padidx[14] = {70,71,142,143,278,279,472,473,474,475,476,477,478,479};
            crow[padidx[lane]] = 0.f;
        }
    } else {
        const int k  = (blockIdx.x - 256) * 4 + (tid >> 6);   // 0..479
        const int n0 = (tid & 63) * 4;
        float4 v = float4{0.f, 0.f, 0.f, 0.f};
        if      (k < 70)              v = *(const float4*)(b0 + (size_t)k * OUTDIM + n0);
        else if (k >= 72  && k < 142) v = *(const float4*)(b1 + (size_t)(k - 72)  * OUTDIM + n0);
        else if (k >= 144 && k < 278) v = *(const float4*)(b2 + (size_t)(k - 144) * OUTDIM + n0);
        else if (k >= 280 && k < 408) v = *(const float4*)(b3 + (size_t)(k - 280) * OUTDIM + n0);
        else if (k >= 408 && k < 472) v = *(const float4*)(b4 + (size_t)(k - 408) * OUTDIM + n0);
        *(float4*)(Bp + (size_t)k * OUTDIM + n0) = v;
    }
}

// ---- prep2: W rows = Wc @ Bp, split to bf16 hi/lo, write MFMA-fragment-packed
// Bpk layout (ushort): [chunk 32][nf 16][h 2][lane 64][j 8]
//   k = chunk*32 + (lane>>4)*8 + j,  n = nf*16 + (lane&15)
extern "C" __global__ __launch_bounds__(256)
void prep2(const float* __restrict__ Wc, const float* __restrict__ Bp,
           ushort* __restrict__ Bpk)
{
    __shared__ float wc[8][KP];
    const int tid = threadIdx.x;
    const int k0  = blockIdx.x * 8;            // 8 W-rows per block
    const int r   = tid >> 5;
    for (int k = (tid & 31); k < KP; k += 32)
        wc[r][k] = Wc[(size_t)(k0 + r) * KP + k];
    __syncthreads();

    float acc[8] = {0,0,0,0,0,0,0,0};
    for (int k = 0; k < KP; ++k) {
        const float b = Bp[(size_t)k * OUTDIM + tid];
        #pragma unroll
        for (int j = 0; j < 8; ++j) acc[j] = fmaf(wc[j][k], b, acc[j]);
    }

    const int chunk = blockIdx.x >> 2, kg = blockIdx.x & 3;
    const int nf = tid >> 4, ln = tid & 15;
    const int lane = kg * 16 + ln;
    ushort h[8], l[8];
    #pragma unroll
    for (int j = 0; j < 8; ++j) {
        h[j] = f2bf_rne(acc[j]);
        l[j] = f2bf_rne(acc[j] - bf2f(h[j]));
    }
    const size_t base = ((size_t)(chunk * 16 + nf) * 2) * 512 + (size_t)lane * 8;
    uint4 hv = { (uint32_t)h[0] | ((uint32_t)h[1] << 16), (uint32_t)h[2] | ((uint32_t)h[3] << 16),
                 (uint32_t)h[4] | ((uint32_t)h[5] << 16), (uint32_t)h[6] | ((uint32_t)h[7] << 16) };
    uint4 lv = { (uint32_t)l[0] | ((uint32_t)l[1] << 16), (uint32_t)l[2] | ((uint32_t)l[3] << 16),
                 (uint32_t)l[4] | ((uint32_t)l[5] << 16), (uint32_t)l[6] | ((uint32_t)l[7] << 16) };
    *(uint4*)(Bpk + base)       = hv;
    *(uint4*)(Bpk + base + 512) = lv;
}

// ---- main: out[16384,256] = x @ W, 3-term bf16-split MFMA -------------------
// BM=64, BN=128, grid (256,2) = 512 blocks -> 2 blocks/CU, 16 waves/CU.
// 8 waves (2m x 4n), wave tile 32x32 (2mf x 2nf), 12 MFMA/wave/chunk.
// LDS 48 KB: B dbuf 32K + A-frag dbuf 16K. ONE barrier per chunk:
//   write staged(c+1) -> issue loads(c+2) -> compute(c) -> barrier.
extern "C" __global__ __launch_bounds__(512, 4)
void wkan_mfma(const float* __restrict__ x, const ushort* __restrict__ Bpk,
               float* __restrict__ out)
{
    __shared__ ushort Bb[2][8][2][64][8];      // [buf][nf_loc][h][lane][j] 32 KB
    __shared__ ushort Ah[2][2][2][2][64][8];   // [buf][wm][mf][h][lane][j] 16 KB

    const int tid  = threadIdx.x;
    const int lane = tid & 63;
    const int wid  = tid >> 6;
    const int wm   = wid >> 2;                 // 0..1
    const int wn   = wid & 3;                  // 0..3
    const int row0 = blockIdx.x * 64;
    const int nf0  = blockIdx.y * 8;           // n-offset = nf0*16

    // A-split duty: thread -> (row, 4 k's); zero redundancy
    const int srow  = tid >> 3;                // 0..63
    const int sk0   = (tid & 7) << 2;          // 0,4,..,28
    const int slane = (sk0 >> 3) * 16 + (srow & 15);
    const int sj0   = sk0 & 7;                 // 0 or 4
    const int swm   = srow >> 5, smf = (srow >> 4) & 1;

    const float*  agp = x + (size_t)(row0 + srow) * INDIM + sk0;
    const ushort* bgp = Bpk + (size_t)nf0 * 1024 + (size_t)tid * 8;

    f32x4 acc[2][2];
    #pragma unroll
    for (int m = 0; m < 2; ++m)
        #pragma unroll
        for (int f = 0; f < 2; ++f) acc[m][f] = f32x4{0.f, 0.f, 0.f, 0.f};

    float4 av; uint4 bv0, bv1;

    // prologue: chunk 0 load + stage, chunk 1 issue
    av  = *(const float4*)(agp);
    bv0 = *(const uint4*)(bgp);
    bv1 = *(const uint4*)(bgp + 4096);
    {
        uint32_t hw0, lw0, hw1, lw1;
        split2(av.x, av.y, hw0, lw0);
        split2(av.z, av.w, hw1, lw1);
        *(uint2*)&Ah[0][swm][smf][0][slane][sj0] = uint2{hw0, hw1};
        *(uint2*)&Ah[0][swm][smf][1][slane][sj0] = uint2{lw0, lw1};
        ushort* bd = &Bb[0][0][0][0][0] + (size_t)tid * 8;
        *(uint4*)bd          = bv0;
        *(uint4*)(bd + 4096) = bv1;
    }
    av  = *(const float4*)(agp + 32);
    bv0 = *(const uint4*)(bgp + 16384);
    bv1 = *(const uint4*)(bgp + 16384 + 4096);
    __syncthreads();

    for (int c = 0; c < 32; ++c) {
        const int cur = c & 1, nx = cur ^ 1;

        // write staged chunk c+1 (regs arrived: drained at previous barrier)
        if (c < 31) {
            uint32_t hw0, lw0, hw1, lw1;
            split2(av.x, av.y, hw0, lw0);
            split2(av.z, av.w, hw1, lw1);
            *(uint2*)&Ah[nx][swm][smf][0][slane][sj0] = uint2{hw0, hw1};
            *(uint2*)&Ah[nx][swm][smf][1][slane][sj0] = uint2{lw0, lw1};
            ushort* bd = &Bb[nx][0][0][0][0] + (size_t)tid * 8;
            *(uint4*)bd          = bv0;
            *(uint4*)(bd + 4096) = bv1;
        }
        // issue loads for chunk c+2 (full-chunk latency window)
        if (c < 30) {
            av = *(const float4*)(agp + (size_t)(c + 2) * 32);
            const ushort* bs = bgp + (size_t)(c + 2) * 16384;
            bv0 = *(const uint4*)bs;
            bv1 = *(const uint4*)(bs + 4096);
        }

        // compute chunk c
        short8 afr[2][2], bfr[2][2];
        #pragma unroll
        for (int m = 0; m < 2; ++m)
            #pragma unroll
            for (int h = 0; h < 2; ++h)
                afr[m][h] = *(const short8*)&Ah[cur][wm][m][h][lane][0];
        #pragma unroll
        for (int f = 0; f < 2; ++f)
            #pragma unroll
            for (int h = 0; h < 2; ++h)
                bfr[f][h] = *(const short8*)&Bb[cur][wn * 2 + f][h][lane][0];

        #pragma unroll
        for (int m = 0; m < 2; ++m)
            #pragma unroll
            for (int f = 0; f < 2; ++f) {
                acc[m][f] = __builtin_amdgcn_mfma_f32_16x16x32_bf16(afr[m][0], bfr[f][0], acc[m][f], 0, 0, 0);
                acc[m][f] = __builtin_amdgcn_mfma_f32_16x16x32_bf16(afr[m][0], bfr[f][1], acc[m][f], 0, 0, 0);
                acc[m][f] = __builtin_amdgcn_mfma_f32_16x16x32_bf16(afr[m][1], bfr[f][0], acc[m][f], 0, 0, 0);
            }
        __syncthreads();
    }

    // C write: D[col = lane&15, row = (lane>>4)*4 + r]  (verified R3)
    #pragma unroll
    for (int m = 0; m < 2; ++m)
        #pragma unroll
        for (int f = 0; f < 2; ++f) {
            const int col  = nf0 * 16 + wn * 32 + f * 16 + (lane & 15);
            const int rowb = row0 + wm * 32 + m * 16 + (lane >> 4) * 4;
            #pragma unroll
            for (int r = 0; r < 4; ++r)
                out[(size_t)(rowb + r) * OUTDIM + col] = acc[m][f][r];
        }
}

// ================= fallback: R1 fused kernel (if ws too small) ===============
constexpr int F_ROWS = 32;
constexpr int F_KP   = 472;

__device__ __forceinline__ void dwt_level_f(const float* __restrict__ in, int N, int M,
                                            float* __restrict__ outA,
                                            float* __restrict__ outD, int nD, int ht) {
    for (int i = ht; i < M; i += 128) {
        const int base = 2 * i - 6;
        float a = 0.f, d = 0.f;
        #pragma unroll
        for (int k = 0; k < 8; ++k) {
            const float v = symx(in, N, base + k);
            a = fmaf(v, LORc[k], a);
            d = fmaf(v, HIRc[k], d);
        }
        outA[i] = a;
        if (i < nD) outD[i] = d;
    }
}

extern "C" __global__ __launch_bounds__(256, 2)
void wkan_fused(const float* __restrict__ x,
                const float* __restrict__ b0, const float* __restrict__ b1,
                const float* __restrict__ b2, const float* __restrict__ b3,
                const float* __restrict__ b4,
                float* __restrict__ out)
{
    extern __shared__ float smem[];
    float* coef = smem;
    float* wbuf = smem + F_ROWS * F_KP;

    const int tid  = threadIdx.x;
    const int row0 = blockIdx.x * F_ROWS;

    for (int i = tid; i < F_ROWS * F_KP / 4; i += 256)
        ((float4*)coef)[i] = float4{0.f, 0.f, 0.f, 0.f};
    __syncthreads();

    const int slot = tid >> 7;
    const int ht   = tid & 127;
    float* bufA = wbuf + slot * 1544;
    float* bufB = bufA + 1024;

    for (int it = 0; it < F_ROWS / 2; ++it) {
        const int r = it * 2 + slot;
        float* crow = coef + r * F_KP;
        const float* xrow = x + (size_t)(row0 + r) * INDIM;
        ((float4*)bufA)[ht]       = ((const float4*)xrow)[ht];
        ((float4*)bufA)[ht + 128] = ((const float4*)xrow)[ht + 128];
        __syncthreads();
        dwt_level_f(bufA, 1024, 515, bufB, crow + 408, 64, ht);
        __syncthreads();
        dwt_level_f(bufB, 515, 261, bufA, crow + 280, 128, ht);
        __syncthreads();
        dwt_level_f(bufA, 261, 134, bufB, crow + 144, 134, ht);
        __syncthreads();
        dwt_level_f(bufB, 134, 70, crow, crow + 72, 70, ht);
        __syncthreads();
    }

    const int rg = tid >> 5;
    const int cg = tid & 31;
    float acc[4][8];
    #pragma unroll
    for (int r = 0; r < 4; ++r)
        #pragma unroll
        for (int c = 0; c < 8; ++c) acc[r][c] = 0.f;

    const float* Bs[5]  = { b0, b1, b2, b3, b4 };
    const int    off[5] = { 0, 72, 144, 280, 408 };
    const int    l4[5]  = { 72, 72, 136, 128, 64 };

    for (int s = 0; s < 5; ++s) {
        const float* __restrict__ B = Bs[s];
        const int o = off[s], L = l4[s];
        for (int k = 0; k < L; k += 4) {
            float4 bb[4][2];
            #pragma unroll
            for (int kk = 0; kk < 4; ++kk) {
                const float* bp = B + (size_t)(k + kk) * OUTDIM + cg * 8;
                bb[kk][0] = *(const float4*)(bp);
                bb[kk][1] = *(const float4*)(bp + 4);
            }
            #pragma unroll
            for (int rr = 0; rr < 4; ++rr) {
                const float4 c4 = *(const float4*)(coef + (rg * 4 + rr) * F_KP + o + k);
                const float cv[4] = { c4.x, c4.y, c4.z, c4.w };
                #pragma unroll
                for (int kk = 0; kk < 4; ++kk) {
                    acc[rr][0] = fmaf(cv[kk], bb[kk][0].x, acc[rr][0]);
                    acc[rr][1] = fmaf(cv[kk], bb[kk][0].y, acc[rr][1]);
                    acc[rr][2] = fmaf(cv[kk], bb[kk][0].z, acc[rr][2]);
                    acc[rr][3] = fmaf(cv[kk], bb[kk][0].w, acc[rr][3]);
                    acc[rr][4] = fmaf(cv[kk], bb[kk][1].x, acc[rr][4]);
                    acc[rr][5] = fmaf(cv[kk], bb[kk][1].y, acc[rr][5]);
                    acc[rr][6] = fmaf(cv[kk], bb[kk][1].z, acc[rr][6]);
                    acc[rr][7] = fmaf(cv[kk], bb[kk][1].w, acc[rr][7]);
                }
            }
        }
    }

    #pragma unroll
    for (int rr = 0; rr < 4; ++rr) {
        float* op = out + (size_t)(row0 + rg * 4 + rr) * OUTDIM + cg * 8;
        *(float4*)(op)     = float4{ acc[rr][0], acc[rr][1], acc[rr][2], acc[rr][3] };
        *(float4*)(op + 4) = float4{ acc[rr][4], acc[rr][5], acc[rr][6], acc[rr][7] };
    }
}

// =============================================================================
extern "C" void kernel_launch(void* const* d_in, const int* in_sizes, int n_in,
                              void* d_out, int out_size, void* d_ws, size_t ws_size,
                              hipStream_t stream) {
    const float* x  = (const float*)d_in[0];
    const float* b0 = (const float*)d_in[1];
    const float* b1 = (const float*)d_in[2];
    const float* b2 = (const float*)d_in[3];
    const float* b3 = (const float*)d_in[4];
    const float* b4 = (const float*)d_in[5];
    float* out = (float*)d_out;

    const size_t nWc  = (size_t)1024 * KP;            // fp32
    const size_t nBp  = (size_t)KP * OUTDIM;          // fp32
    const size_t nBpk = (size_t)1024 * OUTDIM * 2;    // ushort (hi+lo)
    const size_t need = (nWc + nBp) * 4 + nBpk * 2;   // ~3.5 MB

    if (ws_size >= need) {
        float*  Wc  = (float*)d_ws;
        float*  Bp  = Wc + nWc;
        ushort* Bpk = (ushort*)(Bp + nBp);

        hipLaunchKernelGGL(prep1, dim3(376), dim3(256), 0, stream,
                           b0, b1, b2, b3, b4, Wc, Bp);
        hipLaunchKernelGGL(prep2, dim3(128), dim3(256), 0, stream, Wc, Bp, Bpk);
        hipLaunchKernelGGL(wkan_mfma, dim3(BATCH / 64, 2), dim3(512), 0, stream,
                           x, Bpk, out);
    } else {
        const size_t shmem = (size_t)(F_ROWS * F_KP + 2 * 1544) * sizeof(float);
        hipLaunchKernelGGL(wkan_fused, dim3(BATCH / F_ROWS), dim3(256), shmem, stream,
                           x, b0, b1, b2, b3, b4, out);
    }
}

// Round 5
// 159.022 us; speedup vs baseline: 1.3076x; 1.0118x over previous
//
#include <hip/hip_runtime.h>
#include <stdint.h>

#define BATCH   16384
#define INDIM   1024
#define OUTDIM  256

// concatenated-K layout (pads = 0):
//  cA4@0 len70(->72) | cD4@72 len70(->144) | cD3@144 len134(->280) | cD2@280 len128 | cD1@408 len64 (->480)
constexpr int KP = 480;

typedef __attribute__((ext_vector_type(8))) short short8;
typedef __attribute__((ext_vector_type(4))) float f32x4;

// db4 dec filters, correlation form (verified vs jax ref R1-R4)
__device__ __constant__ float LORc[8] = { 0.2303778133088965f,   0.7148465705529157f,
                                          0.6308807679298589f,  -0.027983769416859854f,
                                         -0.18703481171909309f,  0.030841381835560764f,
                                          0.0328830116668852f,  -0.010597401785069032f };
__device__ __constant__ float HIRc[8] = {-0.010597401785069032f, -0.0328830116668852f,
                                          0.030841381835560764f,  0.18703481171909309f,
                                         -0.027983769416859854f, -0.6308807679298589f,
                                          0.7148465705529157f,   -0.2303778133088965f };

__device__ __forceinline__ float symx(const float* __restrict__ in, int N, int t) {
    if (t < 0)  t = -1 - t;
    if (t >= N) t = 2 * N - 1 - t;
    return in[t];
}

__device__ __forceinline__ void dwt_level(const float* __restrict__ in, int N, int M,
                                          float* __restrict__ outA,
                                          float* __restrict__ outD, int nD, int lane) {
    for (int i = lane; i < M; i += 64) {
        const int base = 2 * i - 6;
        float a = 0.f, d = 0.f;
        if (base >= 0 && base + 7 < N) {
            #pragma unroll
            for (int k = 0; k < 8; ++k) {
                const float v = in[base + k];
                a = fmaf(v, LORc[k], a);
                d = fmaf(v, HIRc[k], d);
            }
        } else {
            #pragma unroll
            for (int k = 0; k < 8; ++k) {
                const float v = symx(in, N, base + k);
                a = fmaf(v, LORc[k], a);
                d = fmaf(v, HIRc[k], d);
            }
        }
        outA[i] = a;
        if (i < nD) outD[i] = d;
    }
}

__device__ __forceinline__ ushort f2bf_rne(float f) {
    union { float f; uint32_t u; } v; v.f = f;
    uint32_t r = v.u + 0x7fffu + ((v.u >> 16) & 1u);
    return (ushort)(r >> 16);
}
__device__ __forceinline__ float bf2f(ushort h) {
    union { uint32_t u; float f; } v; v.u = ((uint32_t)h) << 16;
    return v.f;
}

// cheap split: hi = TRUNCATED bf16 (free), lo = RNE(a - hi). lo captures the
// truncation error exactly; total precision ~17 bits, same as RNE/RNE split.
__device__ __forceinline__ void splitc(float a0, float a1, uint32_t& hw, uint32_t& lw) {
    const uint32_t u0 = __float_as_uint(a0), u1 = __float_as_uint(a1);
    hw = (u0 >> 16) | (u1 & 0xffff0000u);
    const float l0 = a0 - __uint_as_float(u0 & 0xffff0000u);
    const float l1 = a1 - __uint_as_float(u1 & 0xffff0000u);
    const uint32_t v0 = __float_as_uint(l0), v1 = __float_as_uint(l1);
    const uint32_t s0 = v0 + 0x7fffu + ((v0 >> 16) & 1u);
    const uint32_t s1 = v1 + 0x7fffu + ((v1 >> 16) & 1u);
    lw = (s0 >> 16) | (s1 & 0xffff0000u);
}

// ---- prep1: blocks 0..255 -> identity DWT rows (Wc); blocks 256..375 -> pack Bp
extern "C" __global__ __launch_bounds__(256)
void prep1(const float* __restrict__ b0, const float* __restrict__ b1,
           const float* __restrict__ b2, const float* __restrict__ b3,
           const float* __restrict__ b4,
           float* __restrict__ Wc, float* __restrict__ Bp)
{
    __shared__ float buf[4][1544];
    const int tid = threadIdx.x;
    if (blockIdx.x < 256) {
        const int wid  = tid >> 6;
        const int lane = tid & 63;
        const int row  = blockIdx.x * 4 + wid;     // identity index 0..1023
        float* bufA = buf[wid];
        float* bufB = bufA + 1024;
        float* crow = Wc + (size_t)row * KP;
        for (int j = lane; j < 1024; j += 64) bufA[j] = (j == row) ? 1.f : 0.f;
        __syncthreads();
        dwt_level(bufA, 1024, 515, bufB, crow + 408, 64, lane);
        __syncthreads();
        dwt_level(bufB, 515, 261, bufA, crow + 280, 128, lane);
        __syncthreads();
        dwt_level(bufA, 261, 134, bufB, crow + 144, 134, lane);
        __syncthreads();
        dwt_level(bufB, 134, 70, crow, crow + 72, 70, lane);
        if (lane < 14) {
            const int padidx[14] = {70,71,142,143,278,279,472,473,474,475,476,477,478,479};
            crow[padidx[lane]] = 0.f;
        }
    } else {
        const int k  = (blockIdx.x - 256) * 4 + (tid >> 6);   // 0..479
        const int n0 = (tid & 63) * 4;
        float4 v = float4{0.f, 0.f, 0.f, 0.f};
        if      (k < 70)              v = *(const float4*)(b0 + (size_t)k * OUTDIM + n0);
        else if (k >= 72  && k < 142) v = *(const float4*)(b1 + (size_t)(k - 72)  * OUTDIM + n0);
        else if (k >= 144 && k < 278) v = *(const float4*)(b2 + (size_t)(k - 144) * OUTDIM + n0);
        else if (k >= 280 && k < 408) v = *(const float4*)(b3 + (size_t)(k - 280) * OUTDIM + n0);
        else if (k >= 408 && k < 472) v = *(const float4*)(b4 + (size_t)(k - 408) * OUTDIM + n0);
        *(float4*)(Bp + (size_t)k * OUTDIM + n0) = v;
    }
}

// ---- prep2: W rows = Wc @ Bp, split to bf16 hi/lo, write MFMA-fragment-packed
// Bpk layout (ushort): [chunk 32][nf 16][h 2][lane 64][j 8]
//   k = chunk*32 + (lane>>4)*8 + j,  n = nf*16 + (lane&15)
extern "C" __global__ __launch_bounds__(256)
void prep2(const float* __restrict__ Wc, const float* __restrict__ Bp,
           ushort* __restrict__ Bpk)
{
    __shared__ float wc[8][KP];
    const int tid = threadIdx.x;
    const int k0  = blockIdx.x * 8;            // 8 W-rows per block
    const int r   = tid >> 5;
    for (int k = (tid & 31); k < KP; k += 32)
        wc[r][k] = Wc[(size_t)(k0 + r) * KP + k];
    __syncthreads();

    float acc[8] = {0,0,0,0,0,0,0,0};
    for (int k = 0; k < KP; ++k) {
        const float b = Bp[(size_t)k * OUTDIM + tid];
        #pragma unroll
        for (int j = 0; j < 8; ++j) acc[j] = fmaf(wc[j][k], b, acc[j]);
    }

    const int chunk = blockIdx.x >> 2, kg = blockIdx.x & 3;
    const int nf = tid >> 4, ln = tid & 15;
    const int lane = kg * 16 + ln;
    ushort h[8], l[8];
    #pragma unroll
    for (int j = 0; j < 8; ++j) {
        h[j] = f2bf_rne(acc[j]);
        l[j] = f2bf_rne(acc[j] - bf2f(h[j]));
    }
    const size_t base = ((size_t)(chunk * 16 + nf) * 2) * 512 + (size_t)lane * 8;
    uint4 hv = { (uint32_t)h[0] | ((uint32_t)h[1] << 16), (uint32_t)h[2] | ((uint32_t)h[3] << 16),
                 (uint32_t)h[4] | ((uint32_t)h[5] << 16), (uint32_t)h[6] | ((uint32_t)h[7] << 16) };
    uint4 lv = { (uint32_t)l[0] | ((uint32_t)l[1] << 16), (uint32_t)l[2] | ((uint32_t)l[3] << 16),
                 (uint32_t)l[4] | ((uint32_t)l[5] << 16), (uint32_t)l[6] | ((uint32_t)l[7] << 16) };
    *(uint4*)(Bpk + base)       = hv;
    *(uint4*)(Bpk + base + 512) = lv;
}

// ---- main: out[16384,256] = x @ W, 3-term bf16-split MFMA -------------------
// BM=64, BN=256 (x read/split ONCE), grid 256, 512 thr = 8 waves (2m x 4n),
// wave tile 32x64 (2mf x 4nf), 24 MFMA/wave/chunk.
// Raw s_barrier + lgkmcnt(0) only (no vmcnt drain): global loads stay in
// flight across barriers. A prefetch depth 4 (regs), B depth 2 (regs).
// LDS 80 KB dynamic: B dbuf 64 KB + A-frag dbuf 16 KB.
extern "C" __global__ __launch_bounds__(512)
void wkan_mfma(const float* __restrict__ x, const ushort* __restrict__ Bpk,
               float* __restrict__ out)
{
    extern __shared__ __align__(16) ushort sm[];
    ushort* Bb0 = sm;              // [2][16 nf][2 h][64 lane][8 j] = 2*16384 us
    ushort* Ah0 = sm + 32768;      // [2][4 mf][2 h][64 lane][8 j] = 2*4096 us

    const int tid  = threadIdx.x;
    const int lane = tid & 63;
    const int wid  = tid >> 6;
    const int wm   = wid >> 2;                 // 0..1
    const int wn   = wid & 3;                  // 0..3
    const int row0 = blockIdx.x * 64;

    // A staging duty: thread -> (row srow, k's sk0..sk0+3); zero redundancy
    const int srow = tid >> 3;                 // 0..63
    const int sk0  = (tid & 7) << 2;           // 0,4,...,28
    const int smf  = srow >> 4;                // 0..3
    const int slan = ((sk0 >> 3) << 4) | (srow & 15);
    const int sj0  = sk0 & 7;                  // 0 or 4
    const int awoff = ((smf * 2 + 0) * 64 + slan) * 8 + sj0;   // h=0 plane; +512 for h=1
    const float*  agp = x + (size_t)(row0 + srow) * INDIM + sk0;
    const ushort* bgp = Bpk + (size_t)tid * 8;

    f32x4 acc[2][4];
    #pragma unroll
    for (int m = 0; m < 2; ++m)
        #pragma unroll
        for (int f = 0; f < 4; ++f) acc[m][f] = f32x4{0.f, 0.f, 0.f, 0.f};

    float4 av[4];
    uint4  bv0, bv1, bv2, bv3;

    // ---- prologue: load+stage chunk 0, prefetch A(1..3), B(1) ----
    av[0] = *(const float4*)agp;
    bv0 = *(const uint4*)(bgp);
    bv1 = *(const uint4*)(bgp + 4096);
    bv2 = *(const uint4*)(bgp + 8192);
    bv3 = *(const uint4*)(bgp + 12288);
    av[1] = *(const float4*)(agp + 32);
    av[2] = *(const float4*)(agp + 64);
    av[3] = *(const float4*)(agp + 96);
    {
        uint32_t hw0, lw0, hw1, lw1;
        splitc(av[0].x, av[0].y, hw0, lw0);
        splitc(av[0].z, av[0].w, hw1, lw1);
        *(uint2*)(Ah0 + awoff)       = uint2{hw0, hw1};
        *(uint2*)(Ah0 + awoff + 512) = uint2{lw0, lw1};
        ushort* bd = Bb0 + tid * 8;
        *(uint4*)(bd)         = bv0;
        *(uint4*)(bd + 4096)  = bv1;
        *(uint4*)(bd + 8192)  = bv2;
        *(uint4*)(bd + 12288) = bv3;
    }
    {
        const ushort* bs = bgp + 16384;
        bv0 = *(const uint4*)(bs);
        bv1 = *(const uint4*)(bs + 4096);
        bv2 = *(const uint4*)(bs + 8192);
        bv3 = *(const uint4*)(bs + 12288);
    }
    asm volatile("s_waitcnt lgkmcnt(0)\n\ts_barrier" ::: "memory");

    #pragma unroll 4
    for (int c = 0; c < 32; ++c) {
        const int cur = c & 1;
        ushort* Bbc = Bb0 + cur * 16384;
        ushort* Ahc = Ah0 + cur * 4096;
        ushort* Bbn = Bb0 + (cur ^ 1) * 16384;
        ushort* Ahn = Ah0 + (cur ^ 1) * 4096;

        // stage chunk c+1 (regs loaded 1-3 chunks ago; compiler waits precisely)
        if (c < 31) {
            const float4 a = av[(c + 1) & 3];
            uint32_t hw0, lw0, hw1, lw1;
            splitc(a.x, a.y, hw0, lw0);
            splitc(a.z, a.w, hw1, lw1);
            *(uint2*)(Ahn + awoff)       = uint2{hw0, hw1};
            *(uint2*)(Ahn + awoff + 512) = uint2{lw0, lw1};
            ushort* bd = Bbn + tid * 8;
            *(uint4*)(bd)         = bv0;
            *(uint4*)(bd + 4096)  = bv1;
            *(uint4*)(bd + 8192)  = bv2;
            *(uint4*)(bd + 12288) = bv3;
        }
        // issue loads: B for c+2, A for c+4 (stay in flight across barriers)
        if (c < 30) {
            const ushort* bs = bgp + (size_t)(c + 2) * 16384;
            bv0 = *(const uint4*)(bs);
            bv1 = *(const uint4*)(bs + 4096);
            bv2 = *(const uint4*)(bs + 8192);
            bv3 = *(const uint4*)(bs + 12288);
        }
        if (c < 28) av[c & 3] = *(const float4*)(agp + (size_t)(c + 4) * 32);

        // compute chunk c
        short8 afr[2][2], bfr[4][2];
        #pragma unroll
        for (int m = 0; m < 2; ++m)
            #pragma unroll
            for (int h = 0; h < 2; ++h)
                afr[m][h] = *(const short8*)(Ahc + (((wm * 2 + m) * 2 + h) * 64 + lane) * 8);
        #pragma unroll
        for (int f = 0; f < 4; ++f)
            #pragma unroll
            for (int h = 0; h < 2; ++h)
                bfr[f][h] = *(const short8*)(Bbc + (((wn * 4 + f) * 2 + h) * 64 + lane) * 8);

        #pragma unroll
        for (int m = 0; m < 2; ++m)
            #pragma unroll
            for (int f = 0; f < 4; ++f) {
                acc[m][f] = __builtin_amdgcn_mfma_f32_16x16x32_bf16(afr[m][0], bfr[f][0], acc[m][f], 0, 0, 0);
                acc[m][f] = __builtin_amdgcn_mfma_f32_16x16x32_bf16(afr[m][0], bfr[f][1], acc[m][f], 0, 0, 0);
                acc[m][f] = __builtin_amdgcn_mfma_f32_16x16x32_bf16(afr[m][1], bfr[f][0], acc[m][f], 0, 0, 0);
            }

        asm volatile("s_waitcnt lgkmcnt(0)\n\ts_barrier" ::: "memory");
    }

    // C write: D[col = lane&15, row = (lane>>4)*4 + r]  (verified R3/R4)
    #pragma unroll
    for (int m = 0; m < 2; ++m)
        #pragma unroll
        for (int f = 0; f < 4; ++f) {
            const int col  = wn * 64 + f * 16 + (lane & 15);
            const int rowb = row0 + wm * 32 + m * 16 + (lane >> 4) * 4;
            #pragma unroll
            for (int r = 0; r < 4; ++r)
                out[(size_t)(rowb + r) * OUTDIM + col] = acc[m][f][r];
        }
}

// ================= fallback: R1 fused kernel (if ws too small) ===============
constexpr int F_ROWS = 32;
constexpr int F_KP   = 472;

__device__ __forceinline__ void dwt_level_f(const float* __restrict__ in, int N, int M,
                                            float* __restrict__ outA,
                                            float* __restrict__ outD, int nD, int ht) {
    for (int i = ht; i < M; i += 128) {
        const int base = 2 * i - 6;
        float a = 0.f, d = 0.f;
        #pragma unroll
        for (int k = 0; k < 8; ++k) {
            const float v = symx(in, N, base + k);
            a = fmaf(v, LORc[k], a);
            d = fmaf(v, HIRc[k], d);
        }
        outA[i] = a;
        if (i < nD) outD[i] = d;
    }
}

extern "C" __global__ __launch_bounds__(256, 2)
void wkan_fused(const float* __restrict__ x,
                const float* __restrict__ b0, const float* __restrict__ b1,
                const float* __restrict__ b2, const float* __restrict__ b3,
                const float* __restrict__ b4,
                float* __restrict__ out)
{
    extern __shared__ float smem[];
    float* coef = smem;
    float* wbuf = smem + F_ROWS * F_KP;

    const int tid  = threadIdx.x;
    const int row0 = blockIdx.x * F_ROWS;

    for (int i = tid; i < F_ROWS * F_KP / 4; i += 256)
        ((float4*)coef)[i] = float4{0.f, 0.f, 0.f, 0.f};
    __syncthreads();

    const int slot = tid >> 7;
    const int ht   = tid & 127;
    float* bufA = wbuf + slot * 1544;
    float* bufB = bufA + 1024;

    for (int it = 0; it < F_ROWS / 2; ++it) {
        const int r = it * 2 + slot;
        float* crow = coef + r * F_KP;
        const float* xrow = x + (size_t)(row0 + r) * INDIM;
        ((float4*)bufA)[ht]       = ((const float4*)xrow)[ht];
        ((float4*)bufA)[ht + 128] = ((const float4*)xrow)[ht + 128];
        __syncthreads();
        dwt_level_f(bufA, 1024, 515, bufB, crow + 408, 64, ht);
        __syncthreads();
        dwt_level_f(bufB, 515, 261, bufA, crow + 280, 128, ht);
        __syncthreads();
        dwt_level_f(bufA, 261, 134, bufB, crow + 144, 134, ht);
        __syncthreads();
        dwt_level_f(bufB, 134, 70, crow, crow + 72, 70, ht);
        __syncthreads();
    }

    const int rg = tid >> 5;
    const int cg = tid & 31;
    float acc[4][8];
    #pragma unroll
    for (int r = 0; r < 4; ++r)
        #pragma unroll
        for (int c = 0; c < 8; ++c) acc[r][c] = 0.f;

    const float* Bs[5]  = { b0, b1, b2, b3, b4 };
    const int    off[5] = { 0, 72, 144, 280, 408 };
    const int    l4[5]  = { 72, 72, 136, 128, 64 };

    for (int s = 0; s < 5; ++s) {
        const float* __restrict__ B = Bs[s];
        const int o = off[s], L = l4[s];
        for (int k = 0; k < L; k += 4) {
            float4 bb[4][2];
            #pragma unroll
            for (int kk = 0; kk < 4; ++kk) {
                const float* bp = B + (size_t)(k + kk) * OUTDIM + cg * 8;
                bb[kk][0] = *(const float4*)(bp);
                bb[kk][1] = *(const float4*)(bp + 4);
            }
            #pragma unroll
            for (int rr = 0; rr < 4; ++rr) {
                const float4 c4 = *(const float4*)(coef + (rg * 4 + rr) * F_KP + o + k);
                const float cv[4] = { c4.x, c4.y, c4.z, c4.w };
                #pragma unroll
                for (int kk = 0; kk < 4; ++kk) {
                    acc[rr][0] = fmaf(cv[kk], bb[kk][0].x, acc[rr][0]);
                    acc[rr][1] = fmaf(cv[kk], bb[kk][0].y, acc[rr][1]);
                    acc[rr][2] = fmaf(cv[kk], bb[kk][0].z, acc[rr][2]);
                    acc[rr][3] = fmaf(cv[kk], bb[kk][0].w, acc[rr][3]);
                    acc[rr][4] = fmaf(cv[kk], bb[kk][1].x, acc[rr][4]);
                    acc[rr][5] = fmaf(cv[kk], bb[kk][1].y, acc[rr][5]);
                    acc[rr][6] = fmaf(cv[kk], bb[kk][1].z, acc[rr][6]);
                    acc[rr][7] = fmaf(cv[kk], bb[kk][1].w, acc[rr][7]);
                }
            }
        }
    }

    #pragma unroll
    for (int rr = 0; rr < 4; ++rr) {
        float* op = out + (size_t)(row0 + rg * 4 + rr) * OUTDIM + cg * 8;
        *(float4*)(op)     = float4{ acc[rr][0], acc[rr][1], acc[rr][2], acc[rr][3] };
        *(float4*)(op + 4) = float4{ acc[rr][4], acc[rr][5], acc[rr][6], acc[rr][7] };
    }
}

// =============================================================================
extern "C" void kernel_launch(void* const* d_in, const int* in_sizes, int n_in,
                              void* d_out, int out_size, void* d_ws, size_t ws_size,
                              hipStream_t stream) {
    const float* x  = (const float*)d_in[0];
    const float* b0 = (const float*)d_in[1];
    const float* b1 = (const float*)d_in[2];
    const float* b2 = (const float*)d_in[3];
    const float* b3 = (const float*)d_in[4];
    const float* b4 = (const float*)d_in[5];
    float* out = (float*)d_out;

    const size_t nWc  = (size_t)1024 * KP;            // fp32
    const size_t nBp  = (size_t)KP * OUTDIM;          // fp32
    const size_t nBpk = (size_t)1024 * OUTDIM * 2;    // ushort (hi+lo)
    const size_t need = (nWc + nBp) * 4 + nBpk * 2;   // ~3.5 MB

    if (ws_size >= need) {
        float*  Wc  = (float*)d_ws;
        float*  Bp  = Wc + nWc;
        ushort* Bpk = (ushort*)(Bp + nBp);

        // 80 KB dynamic LDS needs opt-in (idempotent; capture-safe, not a stream op)
        hipFuncSetAttribute(reinterpret_cast<const void*>(wkan_mfma),
                            hipFuncAttributeMaxDynamicSharedMemorySize, 81920);

        hipLaunchKernelGGL(prep1, dim3(376), dim3(256), 0, stream,
                           b0, b1, b2, b3, b4, Wc, Bp);
        hipLaunchKernelGGL(prep2, dim3(128), dim3(256), 0, stream, Wc, Bp, Bpk);
        hipLaunchKernelGGL(wkan_mfma, dim3(BATCH / 64), dim3(512), 81920, stream,
                           x, Bpk, out);
    } else {
        const size_t shmem = (size_t)(F_ROWS * F_KP + 2 * 1544) * sizeof(float);
        hipLaunchKernelGGL(wkan_fused, dim3(BATCH / F_ROWS), dim3(256), shmem, stream,
                           x, b0, b1, b2, b3, b4, out);
    }
}